// Round 1
// baseline (1378.626 us; speedup 1.0000x reference)
//
#include <hip/hip_runtime.h>
#include <hip/hip_bf16.h>

#define DEVINL __device__ __forceinline__

typedef float f32x4 __attribute__((ext_vector_type(4)));
typedef unsigned short u16x8 __attribute__((ext_vector_type(8)));
typedef __bf16 bf16x8 __attribute__((ext_vector_type(8)));

static constexpr int NN = 40000;     // nodes
static constexpr int NE = 640000;    // edges (divisible by 256)
static constexpr int H  = 128;

// ---- ws layout (bytes) ----
static constexpr long O_HACC = 0;                       // f32 [NN][128]   20,480,000
static constexpr long O_H16  = 20480000;                // bf16 [NN][128]  10,240,000
static constexpr long O_DEG  = 30720000;                // f32 [NN]           160,000
static constexpr long O_WP   = 30880000;                // prepped weights    589,824
static constexpr long O_EA16 = 31469824;                // bf16 [NE][128] 163,840,000
static constexpr long NEED_FULL = O_EA16 + (long)NE * H * 2;  // 195,309,824

// prepped-weight offsets (in ushorts)
static constexpr int WP_E2N1 = 0;
static constexpr int WP_E2N2 = 16384;
static constexpr int WP_EW1  = 32768;    // + l*49152
static constexpr int WP_EW2  = 180224;   // + l*16384
static constexpr int WP_NW   = 229376;   // + l*16384
static constexpr int WP_OW1  = 278528;   // total 294912 ushorts

DEVINL unsigned short f2bf(float f) {
  unsigned int u = __float_as_uint(f);
  u += 0x7fffu + ((u >> 16) & 1u);     // round-to-nearest-even
  return (unsigned short)(u >> 16);
}

DEVINL f32x4 mfma16(u16x8 a, u16x8 b, f32x4 c) {
  return __builtin_amdgcn_mfma_f32_16x16x32_bf16(
      __builtin_bit_cast(bf16x8, a), __builtin_bit_cast(bf16x8, b), c, 0, 0, 0);
}

// ---------------- weight prep ----------------
// mode A (g1):  Wp[((ks*8+nb)*64+l)*8+j] = W[32ks + 8*(l>>4) + j][16nb + (l&15)]
// mode K (kappa): Wp[...]                = W[4ks + (l>>4) + 16j][16nb + (l&15)]
struct PrepPtrs { const float* p[12]; };

__global__ void prep_all(PrepPtrs pp, unsigned short* __restrict__ wp) {
  constexpr int KS[12]   = {4,4, 12,12,12, 4,4,4, 4,4,4, 4};
  constexpr int MODE[12] = {0,1, 0,0,0,    1,1,1, 0,0,0, 0};
  constexpr int OFF[12]  = {WP_E2N1, WP_E2N2,
                            WP_EW1, WP_EW1+49152, WP_EW1+98304,
                            WP_EW2, WP_EW2+16384, WP_EW2+32768,
                            WP_NW,  WP_NW+16384,  WP_NW+32768,
                            WP_OW1};
  int m = blockIdx.y;
  int idx = blockIdx.x * 256 + threadIdx.x;
  if (idx >= KS[m] * 4096) return;
  int j  = idx & 7, l = (idx >> 3) & 63, nb = (idx >> 9) & 7, ks = idx >> 12;
  int hi = l >> 4, lo = l & 15;
  int k = MODE[m] ? (4*ks + hi + 16*j) : (32*ks + 8*hi + j);
  int n = nb*16 + lo;
  wp[OFF[m] + idx] = f2bf(pp.p[m][k*128 + n]);
}

// ---------------- degree ----------------
__global__ void deg_count(const int* __restrict__ dst, float* __restrict__ deg) {
  int e = blockIdx.x * 256 + threadIdx.x;
  unsafeAtomicAdd(&deg[dst[e]], 1.0f);
}
__global__ void deg_invk(float* __restrict__ deg) {
  int i = blockIdx.x * 256 + threadIdx.x;
  if (i < NN) deg[i] = 1.0f / fmaxf(deg[i], 1.0f);
}

// ---------------- h0 convert ----------------
__global__ void cvt_h0(const float* __restrict__ src, unsigned short* __restrict__ dst) {
  long i = ((long)blockIdx.x * 256 + threadIdx.x) * 8;
  f32x4 a = *(const f32x4*)(src + i);
  f32x4 b = *(const f32x4*)(src + i + 4);
  u16x8 t;
  #pragma unroll
  for (int j = 0; j < 4; ++j) { t[j] = f2bf(a[j]); t[4+j] = f2bf(b[j]); }
  *(u16x8*)(dst + i) = t;
}

// ---------------- edge MLP + scatter ----------------
// block: 256 thr / 4 waves, 256 edges; wave-tile 64e x 128n.
// LDS (dynamic 81920B):
//   featP slices: [buf]    at 0      + buf*16384   (pre-fragged, 16KB each)
//   W1 slices:    [buf]    at 32768  + buf*8192
//   sM (overlay of above)  at 0 .. 65536  (256 rows x 256B, sigma-permuted+swizzled)
//   W2 slices:    [buf]    at 65536 + buf*8192
template<int NSRC, bool EA16, bool EA_STORE>
__global__ __launch_bounds__(256, 2) void edge_pass(
    const unsigned short* __restrict__ h16,
    const float* __restrict__ ea32,
    unsigned short* __restrict__ ea16,
    const unsigned short* __restrict__ w1p,
    const unsigned short* __restrict__ w2p,
    const float* __restrict__ b1, const float* __restrict__ b2,
    const int* __restrict__ srcIds, const int* __restrict__ dstIds,
    const float* __restrict__ deg_inv,
    float* __restrict__ target) {
  extern __shared__ char smem[];
  const int tid = threadIdx.x;
  const int wave = tid >> 6, lane = tid & 63;
  const int hi = lane >> 4, lo = lane & 15;
  const long e0 = (long)blockIdx.x * 256;
  constexpr int KS1 = NSRC * 4;

  // ids for staging gathers (thread handles e = i*64 + (tid>>2))
  int dId[4], sId[4];
  if (NSRC == 3) {
    #pragma unroll
    for (int i = 0; i < 4; ++i) {
      int e = i * 64 + (tid >> 2);
      dId[i] = dstIds[e0 + e];
      sId[i] = srcIds[e0 + e];
    }
  }
  float b1v[8], b2v[8];
  #pragma unroll
  for (int nb = 0; nb < 8; ++nb) { b1v[nb] = b1[nb*16 + lo]; b2v[nb] = b2[nb*16 + lo]; }

  f32x4 acc[4][8];
  #pragma unroll
  for (int mf = 0; mf < 4; ++mf)
    #pragma unroll
    for (int nb = 0; nb < 8; ++nb) acc[mf][nb] = (f32x4)(0.0f);

  const int eTh = (tid >> 2);       // 0..63
  const int qTh = (tid & 3);        // 0..3

  u16x8 sv[4], wv[2];
  // ---- slice loader (global -> regs) ----
  auto load_slice = [&](int s, u16x8 (&v)[4]) {
    int ssel = s >> 2, inner = (s & 3) * 32;
    #pragma unroll
    for (int i = 0; i < 4; ++i) {
      int e = i * 64 + eTh;
      if (NSRC == 1 || ssel == 2) {
        long base = (e0 + e) * 128 + inner + qTh * 8;
        if (EA16) {
          v[i] = *(const u16x8*)(ea16 + base);
        } else {
          f32x4 f0 = *(const f32x4*)(ea32 + base);
          f32x4 f1 = *(const f32x4*)(ea32 + base + 4);
          u16x8 t;
          #pragma unroll
          for (int j = 0; j < 4; ++j) { t[j] = f2bf(f0[j]); t[4+j] = f2bf(f1[j]); }
          if (EA_STORE) *(u16x8*)(ea16 + base) = t;
          v[i] = t;
        }
      } else {
        int row = (ssel == 0) ? dId[i] : sId[i];
        v[i] = *(const u16x8*)(h16 + (long)row * 128 + inner + qTh * 8);
      }
    }
  };
  auto write_slice = [&](int s, u16x8 (&v)[4]) {
    char* buf = smem + (s & 1) * 16384;
    #pragma unroll
    for (int i = 0; i < 4; ++i) {
      int e = i * 64 + eTh;
      *(u16x8*)(buf + (((e >> 4) * 64 + qTh * 16 + (e & 15)) << 4)) = v[i];
    }
  };
  auto load_w = [&](const unsigned short* wp_, int s, u16x8 (&w)[2]) {
    const u16x8* p = (const u16x8*)(wp_ + (long)s * 4096);
    w[0] = p[tid]; w[1] = p[tid + 256];
  };
  auto write_w = [&](long base, int buf, u16x8 (&w)[2]) {
    u16x8* p = (u16x8*)(smem + base + buf * 8192);
    p[tid] = w[0]; p[tid + 256] = w[1];
  };

  // ---- GEMM1: feat[256x(NSRC*128)] @ W1 -> relu -> sM ----
  load_slice(0, sv); load_w(w1p, 0, wv);
  write_slice(0, sv); write_w(32768, 0, wv);
  __syncthreads();

  for (int s = 0; s < KS1; ++s) {
    u16x8 nsv[4], nwv[2];
    if (s + 1 < KS1) { load_slice(s + 1, nsv); load_w(w1p, s + 1, nwv); }
    const char* fb = smem + (s & 1) * 16384;
    const char* wb = smem + 32768 + (s & 1) * 8192;
    u16x8 af[4], bf[8];
    #pragma unroll
    for (int mf = 0; mf < 4; ++mf)
      af[mf] = *(const u16x8*)(fb + ((4 * wave + mf) << 10) + (lane << 4));
    #pragma unroll
    for (int nb = 0; nb < 8; ++nb)
      bf[nb] = *(const u16x8*)(wb + (nb << 10) + (lane << 4));
    #pragma unroll
    for (int mf = 0; mf < 4; ++mf)
      #pragma unroll
      for (int nb = 0; nb < 8; ++nb)
        acc[mf][nb] = mfma16(af[mf], bf[nb], acc[mf][nb]);
    if (s + 1 < KS1) { write_slice(s + 1, nsv); write_w(32768, (s + 1) & 1, nwv); }
    __syncthreads();
  }

  // ---- epilogue1: bias+relu -> bf16 -> sM (sigma layout + XOR swizzle) ----
  #pragma unroll
  for (int mf = 0; mf < 4; ++mf) {
    #pragma unroll
    for (int r = 0; r < 4; ++r) {
      int er = 64 * wave + 16 * mf + 4 * hi + r;
      u16x8 pack;
      #pragma unroll
      for (int nb = 0; nb < 8; ++nb) {
        float v = fmaxf(acc[mf][nb][r] + b1v[nb], 0.0f);
        pack[nb] = f2bf(v);
      }
      *(u16x8*)(smem + er * 256 + ((lo * 16) ^ ((er & 7) << 4))) = pack;
    }
  }
  #pragma unroll
  for (int mf = 0; mf < 4; ++mf)
    #pragma unroll
    for (int nb = 0; nb < 8; ++nb) acc[mf][nb] = (f32x4)(0.0f);

  { u16x8 w2v[2]; load_w(w2p, 0, w2v); write_w(65536, 0, w2v); }
  __syncthreads();

  // ---- GEMM2: m[256x128] @ W2 ----
  for (int s = 0; s < 4; ++s) {
    u16x8 nwv[2];
    if (s < 3) load_w(w2p, s + 1, nwv);
    const char* wb = smem + 65536 + (s & 1) * 8192;
    u16x8 af[4], bf[8];
    #pragma unroll
    for (int mf = 0; mf < 4; ++mf) {
      int e = 64 * wave + 16 * mf + lo;
      af[mf] = *(const u16x8*)(smem + e * 256 + (((4 * s + hi) * 16) ^ ((e & 7) << 4)));
    }
    #pragma unroll
    for (int nb = 0; nb < 8; ++nb)
      bf[nb] = *(const u16x8*)(wb + (nb << 10) + (lane << 4));
    #pragma unroll
    for (int mf = 0; mf < 4; ++mf)
      #pragma unroll
      for (int nb = 0; nb < 8; ++nb)
        acc[mf][nb] = mfma16(af[mf], bf[nb], acc[mf][nb]);
    if (s < 3) write_w(65536, (s + 1) & 1, nwv);
    __syncthreads();
  }

  // ---- epilogue2: bias, deg-scale, atomic scatter ----
  int dE[4][4]; float scl[4][4];
  #pragma unroll
  for (int mf = 0; mf < 4; ++mf)
    #pragma unroll
    for (int r = 0; r < 4; ++r) {
      int e = 64 * wave + 16 * mf + 4 * hi + r;
      int d = dstIds[e0 + e];
      dE[mf][r] = d;
      scl[mf][r] = (NSRC == 3) ? deg_inv[d] : 1.0f;
    }
  #pragma unroll
  for (int mf = 0; mf < 4; ++mf)
    #pragma unroll
    for (int nb = 0; nb < 8; ++nb)
      #pragma unroll
      for (int r = 0; r < 4; ++r) {
        float v = (acc[mf][nb][r] + b2v[nb]) * scl[mf][r];
        unsafeAtomicAdd(&target[(long)dE[mf][r] * 128 + nb * 16 + lo], v);
      }
}

// ---------------- node MLP: h16 = relu(agg @ Wn + bn) ----------------
__global__ __launch_bounds__(256) void node_pass(
    const float* __restrict__ agg, const unsigned short* __restrict__ wp,
    const float* __restrict__ bias, unsigned short* __restrict__ h16out) {
  __shared__ char smem[49152];   // aggP 16KB + Wn 32KB
  const int tid = threadIdx.x;
  const int wave = tid >> 6, lane = tid & 63;
  const int hi = lane >> 4, lo = lane & 15;
  const int n0 = blockIdx.x * 64;
  const int r = tid >> 2, q = tid & 3;

  #pragma unroll
  for (int s = 0; s < 4; ++s) {
    f32x4 f0 = *(const f32x4*)(agg + (long)(n0 + r) * 128 + s * 32 + q * 8);
    f32x4 f1 = *(const f32x4*)(agg + (long)(n0 + r) * 128 + s * 32 + q * 8 + 4);
    u16x8 t;
    #pragma unroll
    for (int j = 0; j < 4; ++j) { t[j] = f2bf(f0[j]); t[4+j] = f2bf(f1[j]); }
    *(u16x8*)(smem + s * 4096 + (((r >> 4) * 64 + q * 16 + (r & 15)) << 4)) = t;
  }
  {
    const u16x8* g = (const u16x8*)wp;
    u16x8* l = (u16x8*)(smem + 16384);
    #pragma unroll
    for (int i = 0; i < 8; ++i) l[i * 256 + tid] = g[i * 256 + tid];
  }
  __syncthreads();

  f32x4 acc[8];
  #pragma unroll
  for (int nb = 0; nb < 8; ++nb) acc[nb] = (f32x4)(0.0f);
  #pragma unroll
  for (int s = 0; s < 4; ++s) {
    u16x8 a = *(const u16x8*)(smem + s * 4096 + wave * 1024 + (lane << 4));
    #pragma unroll
    for (int nb = 0; nb < 8; ++nb) {
      u16x8 b = *(const u16x8*)(smem + 16384 + ((s * 8 + nb) << 10) + (lane << 4));
      acc[nb] = mfma16(a, b, acc[nb]);
    }
  }
  float bv[8];
  #pragma unroll
  for (int nb = 0; nb < 8; ++nb) bv[nb] = bias[nb * 16 + lo];
  #pragma unroll
  for (int nb = 0; nb < 8; ++nb)
    #pragma unroll
    for (int rr = 0; rr < 4; ++rr) {
      int node = n0 + 16 * wave + 4 * hi + rr;
      float v = fmaxf(acc[nb][rr] + bv[nb], 0.0f);
      h16out[(long)node * 128 + nb * 16 + lo] = f2bf(v);
    }
}

// ---------------- output head ----------------
__global__ __launch_bounds__(256) void out_pass(
    const unsigned short* __restrict__ h16, const unsigned short* __restrict__ wp,
    const float* __restrict__ ob1, const float* __restrict__ oW2,
    const float* __restrict__ ob2, float* __restrict__ out) {
  __shared__ char smem[49152];
  const int tid = threadIdx.x;
  const int wave = tid >> 6, lane = tid & 63;
  const int hi = lane >> 4, lo = lane & 15;
  const int n0 = blockIdx.x * 64;
  const int r = tid >> 2, q = tid & 3;

  #pragma unroll
  for (int s = 0; s < 4; ++s) {
    u16x8 t = *(const u16x8*)(h16 + (long)(n0 + r) * 128 + s * 32 + q * 8);
    *(u16x8*)(smem + s * 4096 + (((r >> 4) * 64 + q * 16 + (r & 15)) << 4)) = t;
  }
  {
    const u16x8* g = (const u16x8*)wp;
    u16x8* l = (u16x8*)(smem + 16384);
    #pragma unroll
    for (int i = 0; i < 8; ++i) l[i * 256 + tid] = g[i * 256 + tid];
  }
  __syncthreads();

  f32x4 acc[8];
  #pragma unroll
  for (int nb = 0; nb < 8; ++nb) acc[nb] = (f32x4)(0.0f);
  #pragma unroll
  for (int s = 0; s < 4; ++s) {
    u16x8 a = *(const u16x8*)(smem + s * 4096 + wave * 1024 + (lane << 4));
    #pragma unroll
    for (int nb = 0; nb < 8; ++nb) {
      u16x8 b = *(const u16x8*)(smem + 16384 + ((s * 8 + nb) << 10) + (lane << 4));
      acc[nb] = mfma16(a, b, acc[nb]);
    }
  }
  float b1v[8], w2v[8][3];
  #pragma unroll
  for (int nb = 0; nb < 8; ++nb) {
    b1v[nb] = ob1[nb * 16 + lo];
    #pragma unroll
    for (int o = 0; o < 3; ++o) w2v[nb][o] = oW2[(nb * 16 + lo) * 3 + o];
  }
  #pragma unroll
  for (int rr = 0; rr < 4; ++rr) {
    float p0 = 0.f, p1 = 0.f, p2 = 0.f;
    #pragma unroll
    for (int nb = 0; nb < 8; ++nb) {
      float t = fmaxf(acc[nb][rr] + b1v[nb], 0.0f);
      p0 += t * w2v[nb][0]; p1 += t * w2v[nb][1]; p2 += t * w2v[nb][2];
    }
    #pragma unroll
    for (int off = 1; off < 16; off <<= 1) {
      p0 += __shfl_xor(p0, off); p1 += __shfl_xor(p1, off); p2 += __shfl_xor(p2, off);
    }
    if (lo == 0) {
      int node = n0 + 16 * wave + 4 * hi + rr;
      out[(long)node * 3 + 0] = p0 + ob2[0];
      out[(long)node * 3 + 1] = p1 + ob2[1];
      out[(long)node * 3 + 2] = p2 + ob2[2];
    }
  }
}

// ---------------- host ----------------
extern "C" void kernel_launch(void* const* d_in, const int* in_sizes, int n_in,
                              void* d_out, int out_size, void* d_ws, size_t ws_size,
                              hipStream_t stream) {
  const int*   ei     = (const int*)d_in[1];
  const int*   srcIds = ei;
  const int*   dstIds = ei + NE;
  const float* ea     = (const float*)d_in[2];
  const float* e2nb1  = (const float*)d_in[4];
  const float* e2nb2  = (const float*)d_in[6];
  const float* eW1    = (const float*)d_in[7];
  const float* eb1    = (const float*)d_in[8];
  const float* eW2    = (const float*)d_in[9];
  const float* eb2    = (const float*)d_in[10];
  const float* nW     = (const float*)d_in[11];
  const float* nb_    = (const float*)d_in[12];
  const float* ob1    = (const float*)d_in[14];
  const float* oW2    = (const float*)d_in[15];
  const float* ob2    = (const float*)d_in[16];
  float* out = (float*)d_out;

  char* ws = (char*)d_ws;
  float* hacc = (float*)(ws + O_HACC);
  unsigned short* h16 = (unsigned short*)(ws + O_H16);
  float* deg = (float*)(ws + O_DEG);
  unsigned short* wp = (unsigned short*)(ws + O_WP);
  unsigned short* ea16 = (unsigned short*)(ws + O_EA16);
  const bool ea16en = (ws_size >= (size_t)NEED_FULL);

  PrepPtrs pp;
  pp.p[0] = (const float*)d_in[3];
  pp.p[1] = (const float*)d_in[5];
  pp.p[2] = eW1; pp.p[3] = eW1 + 49152; pp.p[4] = eW1 + 98304;
  pp.p[5] = eW2; pp.p[6] = eW2 + 16384; pp.p[7] = eW2 + 32768;
  pp.p[8] = nW;  pp.p[9] = nW  + 16384; pp.p[10] = nW + 32768;
  pp.p[11] = (const float*)d_in[13];

  hipMemsetAsync(hacc, 0, (size_t)NN * H * 4, stream);
  hipMemsetAsync(deg, 0, (size_t)NN * 4, stream);
  prep_all<<<dim3(192, 12), 256, 0, stream>>>(pp, wp);
  deg_count<<<NE / 256, 256, 0, stream>>>(dstIds, deg);
  deg_invk<<<(NN + 255) / 256, 256, 0, stream>>>(deg);

  // e2n edge MLP -> scatter-add into hacc (also converts ea -> bf16 if room)
  if (ea16en)
    edge_pass<1, false, true><<<NE / 256, 256, 81920, stream>>>(
        h16, ea, ea16, wp + WP_E2N1, wp + WP_E2N2, e2nb1, e2nb2,
        srcIds, dstIds, nullptr, hacc);
  else
    edge_pass<1, false, false><<<NE / 256, 256, 81920, stream>>>(
        h16, ea, nullptr, wp + WP_E2N1, wp + WP_E2N2, e2nb1, e2nb2,
        srcIds, dstIds, nullptr, hacc);

  cvt_h0<<<NN * H / (256 * 8), 256, 0, stream>>>(hacc, h16);

  for (int l = 0; l < 3; ++l) {
    hipMemsetAsync(hacc, 0, (size_t)NN * H * 4, stream);
    if (ea16en)
      edge_pass<3, true, false><<<NE / 256, 256, 81920, stream>>>(
          h16, ea, ea16, wp + WP_EW1 + l * 49152, wp + WP_EW2 + l * 16384,
          eb1 + l * 128, eb2 + l * 128, srcIds, dstIds, deg, hacc);
    else
      edge_pass<3, false, false><<<NE / 256, 256, 81920, stream>>>(
          h16, ea, nullptr, wp + WP_EW1 + l * 49152, wp + WP_EW2 + l * 16384,
          eb1 + l * 128, eb2 + l * 128, srcIds, dstIds, deg, hacc);
    node_pass<<<NN / 64, 256, 0, stream>>>(hacc, wp + WP_NW + l * 16384,
                                           nb_ + l * 128, h16);
  }

  out_pass<<<NN / 64, 256, 0, stream>>>(h16, wp + WP_OW1, ob1, oW2, ob2, out);
}